// Round 11
// baseline (332.374 us; speedup 1.0000x reference)
//
#include <hip/hip_runtime.h>

#define TT 168
#define HH 64
#define DD 7
#define NS 32      // samples per block: 2 N=16 MFMA sample-tiles
#define BB 8192
#define NTH 512    // waves 0-3: layer0 engine; waves 4-7: layer1 engine

typedef float f32x4 __attribute__((ext_vector_type(4)));
typedef _Float16 f16x8 __attribute__((ext_vector_type(8)));

#define MFMA16F(A, B, C) __builtin_amdgcn_mfma_f32_16x16x32_f16((A), (B), (C), 0, 0, 0)

// weights split hi+lo fp16 (covers fp32 mantissa), data single fp16
#define TERM2(G, Wh, Wl, D)   \
    G = MFMA16F(Wh, (D), G);  \
    G = MFMA16F(Wl, (D), G);

// weight split: hi = RTNE fp16, lo = residual
__device__ __forceinline__ void wsplit8(f32x4 a, f32x4 b, f16x8& hi, f16x8& lo) {
#pragma unroll
    for (int e = 0; e < 4; ++e) {
        const _Float16 h = (_Float16)a[e];
        hi[e] = h; lo[e] = (_Float16)(a[e] - (float)h);
    }
#pragma unroll
    for (int e = 0; e < 4; ++e) {
        const _Float16 h = (_Float16)b[e];
        hi[4 + e] = h; lo[4 + e] = (_Float16)(b[e] - (float)h);
    }
}
__device__ __forceinline__ f16x8 pack8(f32x4 a, f32x4 b) {
    f16x8 r;
#pragma unroll
    for (int e = 0; e < 4; ++e) { r[e] = (_Float16)a[e]; r[4 + e] = (_Float16)b[e]; }
    return r;
}

// clamped exp2 (NaN-proof saturation: 2^80 stays finite through products)
__device__ __forceinline__ float e2c(float a) {
    return __builtin_amdgcn_exp2f(fminf(a, 80.0f));
}

// cell update (4 units, 1 sample), 7 transcendentals/element via shared rcp:
//   sig(x) = 1/(1+u),  tanh(x) = (1-u2)/(1+u2),  u = 2^(-1.4427 x), u2 = 2^(-2.8854 x)
//   R = rcp((1+ui)(1+ug)(1+uf)):  f = (1+ui)(1+ug)R,  i*g = (1-ug)(1+uf)R
//   R2 = rcp((1+uo)(1+uc)):       h = o*tanh(c) = (1-uc)R2
__device__ __forceinline__ void cell_update(const f32x4& gi, const f32x4& gf,
                                            const f32x4& gg, const f32x4& go,
                                            f32x4& cst, _Float16* dst) {
    f32x4 hv;
#pragma unroll
    for (int r = 0; r < 4; ++r) {
        const float ui  = e2c(gi[r] * -1.44269504f);
        const float ug  = e2c(gg[r] * -2.88539008f);
        const float uf  = e2c(gf[r] * -1.44269504f);
        const float opf = 1.0f + uf;
        const float tig = (1.0f + ui) * (1.0f + ug);
        const float R1  = __builtin_amdgcn_rcpf(tig * opf);
        const float fv  = tig * R1;
        const float ig  = (1.0f - ug) * opf * R1;
        cst[r] = fv * cst[r] + ig;
        const float uo = e2c(go[r] * -1.44269504f);
        const float uc = e2c(cst[r] * -2.88539008f);
        const float R2 = __builtin_amdgcn_rcpf((1.0f + uo) * (1.0f + uc));
        hv[r] = (1.0f - uc) * R2;
    }
    unsigned d0, d1;
    asm("v_cvt_pkrtz_f16_f32 %0, %1, %2" : "=v"(d0) : "v"(hv[0]), "v"(hv[1]));
    asm("v_cvt_pkrtz_f16_f32 %0, %1, %2" : "=v"(d1) : "v"(hv[2]), "v"(hv[3]));
    *(uint2*)dst = make_uint2(d0, d1);
}

__global__ __launch_bounds__(NTH, 2)
void weather_lstm_mfma(const float* __restrict__ x,
                       const float* __restrict__ w_ih0, const float* __restrict__ w_hh0,
                       const float* __restrict__ b_ih0, const float* __restrict__ b_hh0,
                       const float* __restrict__ w_ih1, const float* __restrict__ w_hh1,
                       const float* __restrict__ b_ih1, const float* __restrict__ b_hh1,
                       const float* __restrict__ fc_w, const float* __restrict__ fc_b,
                       float* __restrict__ out)
{
    __shared__ f16x8 xs[TT][NS];                              // 86 KB: ALL x, frag-ready
    __shared__ __align__(16) _Float16 h1[2][NS][72];          // 9.2 KB (144B rows)
    __shared__ __align__(16) _Float16 h2[2][NS][72];          // 9.2 KB

    const int tid  = threadIdx.x;
    const int wv   = tid >> 6;       // 0..7
    const int q    = wv & 3;         // unit group within the engine
    const int lane = tid & 63;
    const int col  = lane & 15;      // weight row within tile / sample within stile
    const int kg   = lane >> 4;      // k-group
    const int s0   = blockIdx.x * NS;
    const int ub   = 16 * q + 4 * kg;

    // ---------------- init: zero h (both parities), pre-stage ALL x ----------------
    for (int i = tid; i < 2 * NS * 72; i += NTH) {
        ((short*)h1)[i] = 0; ((short*)h2)[i] = 0;
    }
    for (int i = tid; i < NS * TT; i += NTH) {
        const int s = i / TT, t = i - s * TT;
        const float* px = x + ((size_t)(s0 + s) * TT + t) * DD;
        f32x4 a, b;
        a[0] = px[0]; a[1] = px[1]; a[2] = px[2]; a[3] = px[3];
        b[0] = px[4]; b[1] = px[5]; b[2] = px[6]; b[3] = 1.0f;   // bias slot
        xs[t][s] = pack8(a, b);
    }
    __syncthreads();

    const f16x8 z8 = {0, 0, 0, 0, 0, 0, 0, 0};
    const f32x4 zz = {0, 0, 0, 0};

    if (wv < 4) {
        // ==================== LAYER-0 ENGINE (waves 0-3) ====================
        f16x8 W0h[4][2], W0l[4][2];   // w_hh0 (K=64)
        f16x8 WXh[4],    WXl[4];      // w_ih0 + bias0 in k-slot 7
#pragma unroll
        for (int t4 = 0; t4 < 4; ++t4) {
            const int row = 64 * t4 + 16 * q + col;
#pragma unroll
            for (int kf = 0; kf < 2; ++kf) {
                const float* p = w_hh0 + (size_t)row * HH + 32 * kf + 8 * kg;
                wsplit8(*(const f32x4*)p, *(const f32x4*)(p + 4), W0h[t4][kf], W0l[t4][kf]);
            }
            f32x4 a = {0, 0, 0, 0}, b = {0, 0, 0, 0};
            if (kg == 0) {
                const float* p = w_ih0 + (size_t)row * DD;
                a[0] = p[0]; a[1] = p[1]; a[2] = p[2]; a[3] = p[3];
                b[0] = p[4]; b[1] = p[5]; b[2] = p[6];
                b[3] = b_ih0[row] + b_hh0[row];     // bias0 rides k-slot 7
            }
            wsplit8(a, b, WXh[t4], WXl[t4]);
        }
        f32x4 c1[2] = {{0,0,0,0},{0,0,0,0}};

#pragma unroll 1
        for (int k = 0; k <= TT + 1; ++k) {
            f32x4 aA[2][4];
            // ---------- Segment A: L0 MFMA for step k ----------
            if (k < TT) {
                const int rp = (k - 1) & 1;             // h1(k-1) parity
                __builtin_amdgcn_s_setprio(1);
#pragma unroll
                for (int st = 0; st < 2; ++st) {
                    f16x8 ax = z8;
                    if (kg == 0) ax = xs[k][16 * st + col];
                    aA[st][0] = MFMA16F(WXh[0], ax, zz); aA[st][0] = MFMA16F(WXl[0], ax, aA[st][0]);
                    aA[st][1] = MFMA16F(WXh[1], ax, zz); aA[st][1] = MFMA16F(WXl[1], ax, aA[st][1]);
                    aA[st][2] = MFMA16F(WXh[2], ax, zz); aA[st][2] = MFMA16F(WXl[2], ax, aA[st][2]);
                    aA[st][3] = MFMA16F(WXh[3], ax, zz); aA[st][3] = MFMA16F(WXl[3], ax, aA[st][3]);
#pragma unroll
                    for (int kf = 0; kf < 2; ++kf) {
                        const f16x8 dh = *(const f16x8*)&h1[rp][16 * st + col][32 * kf + 8 * kg];
                        TERM2(aA[st][0], W0h[0][kf], W0l[0][kf], dh)
                        TERM2(aA[st][1], W0h[1][kf], W0l[1][kf], dh)
                        TERM2(aA[st][2], W0h[2][kf], W0l[2][kf], dh)
                        TERM2(aA[st][3], W0h[3][kf], W0l[3][kf], dh)
                    }
                }
                __builtin_amdgcn_s_setprio(0);
            }
            __syncthreads();   // B1
            // ---------- Segment B: L0 cell update for step k ----------
            if (k < TT) {
                const int wp = k & 1;
#pragma unroll
                for (int st = 0; st < 2; ++st)
                    cell_update(aA[st][0], aA[st][1], aA[st][2], aA[st][3], c1[st],
                                &h1[wp][16 * st + col][ub]);
            }
            __syncthreads();   // B2
        }
    } else {
        // ==================== LAYER-1 ENGINE (waves 4-7) ====================
        f16x8 W1h[4][4], W1l[4][4];   // kf 0..1: w_ih1 (h1 input); kf 2..3: w_hh1 (h2 input)
        f32x4 bias1[4];
#pragma unroll
        for (int t4 = 0; t4 < 4; ++t4) {
            const int row = 64 * t4 + 16 * q + col;
            const int rr  = 64 * t4 + 16 * q + 4 * kg;
            bias1[t4] = *(const f32x4*)(b_ih1 + rr) + *(const f32x4*)(b_hh1 + rr);
#pragma unroll
            for (int kf = 0; kf < 4; ++kf) {
                const float* base = (kf < 2) ? (w_ih1 + (size_t)row * HH + 32 * kf)
                                             : (w_hh1 + (size_t)row * HH + 32 * (kf - 2));
                const float* p = base + 8 * kg;
                wsplit8(*(const f32x4*)p, *(const f32x4*)(p + 4), W1h[t4][kf], W1l[t4][kf]);
            }
        }
        f32x4 c2[2] = {{0,0,0,0},{0,0,0,0}};
        f32x4 aB[2][4];

#pragma unroll 1
        for (int k = 0; k <= TT + 1; ++k) {
            // ---------- Segment A: L1 cell update for step k-2 (reads aB) ----------
            if (k >= 2) {
                const int wp = k & 1;                   // (k-2)&1
#pragma unroll
                for (int st = 0; st < 2; ++st)
                    cell_update(aB[st][0], aB[st][1], aB[st][2], aB[st][3], c2[st],
                                &h2[wp][16 * st + col][ub]);
            }
            __syncthreads();   // B1
            // ---------- Segment B: L1 MFMA for step k-1 (C-init = bias) ----------
            if (k >= 1 && k <= TT) {
                const int rp1 = (k - 1) & 1;            // h1(k-1) parity
                const int rp2 = k & 1;                  // h2(k-2) parity
                __builtin_amdgcn_s_setprio(1);
#pragma unroll
                for (int st = 0; st < 2; ++st) {
                    {
                        const f16x8 dh = *(const f16x8*)&h1[rp1][16 * st + col][8 * kg];
                        aB[st][0] = MFMA16F(W1h[0][0], dh, bias1[0]); aB[st][0] = MFMA16F(W1l[0][0], dh, aB[st][0]);
                        aB[st][1] = MFMA16F(W1h[1][0], dh, bias1[1]); aB[st][1] = MFMA16F(W1l[1][0], dh, aB[st][1]);
                        aB[st][2] = MFMA16F(W1h[2][0], dh, bias1[2]); aB[st][2] = MFMA16F(W1l[2][0], dh, aB[st][2]);
                        aB[st][3] = MFMA16F(W1h[3][0], dh, bias1[3]); aB[st][3] = MFMA16F(W1l[3][0], dh, aB[st][3]);
                    }
                    {
                        const f16x8 dh = *(const f16x8*)&h1[rp1][16 * st + col][32 + 8 * kg];
                        TERM2(aB[st][0], W1h[0][1], W1l[0][1], dh)
                        TERM2(aB[st][1], W1h[1][1], W1l[1][1], dh)
                        TERM2(aB[st][2], W1h[2][1], W1l[2][1], dh)
                        TERM2(aB[st][3], W1h[3][1], W1l[3][1], dh)
                    }
#pragma unroll
                    for (int kf = 0; kf < 2; ++kf) {    // h2(k-2) input
                        const f16x8 eh = *(const f16x8*)&h2[rp2][16 * st + col][32 * kf + 8 * kg];
                        TERM2(aB[st][0], W1h[0][kf + 2], W1l[0][kf + 2], eh)
                        TERM2(aB[st][1], W1h[1][kf + 2], W1l[1][kf + 2], eh)
                        TERM2(aB[st][2], W1h[2][kf + 2], W1l[2][kf + 2], eh)
                        TERM2(aB[st][3], W1h[3][kf + 2], W1l[3][kf + 2], eh)
                    }
                }
                __builtin_amdgcn_s_setprio(0);
            }
            __syncthreads();   // B2
        }
    }

    // ---------------- FC head on final h2 = h2(TT-1), parity 1 ----------------
    if (tid < NS * 4) {
        const int s = tid >> 2, k = tid & 3;
        float a = fc_b[k];
#pragma unroll
        for (int j = 0; j < HH; ++j)
            a = fmaf((float)h2[1][s][j], fc_w[k * HH + j], a);
        out[(size_t)(s0 + s) * 4 + k] = a;
    }
}

extern "C" void kernel_launch(void* const* d_in, const int* in_sizes, int n_in,
                              void* d_out, int out_size, void* d_ws, size_t ws_size,
                              hipStream_t stream) {
    const float* x     = (const float*)d_in[0];
    const float* w_ih0 = (const float*)d_in[1];
    const float* w_hh0 = (const float*)d_in[2];
    const float* b_ih0 = (const float*)d_in[3];
    const float* b_hh0 = (const float*)d_in[4];
    const float* w_ih1 = (const float*)d_in[5];
    const float* w_hh1 = (const float*)d_in[6];
    const float* b_ih1 = (const float*)d_in[7];
    const float* b_hh1 = (const float*)d_in[8];
    const float* fc_w  = (const float*)d_in[9];
    const float* fc_b  = (const float*)d_in[10];
    float* out = (float*)d_out;

    dim3 grid(BB / NS), block(NTH);
    weather_lstm_mfma<<<grid, block, 0, stream>>>(
        x, w_ih0, w_hh0, b_ih0, b_hh0,
        w_ih1, w_hh1, b_ih1, b_hh1, fc_w, fc_b, out);
}

// Round 12
// 249.932 us; speedup vs baseline: 1.3299x; 1.3299x over previous
//
#include <hip/hip_runtime.h>

#define TT 168
#define HH 64
#define DD 7
#define NS 16      // samples per block: ONE N=16 MFMA sample-tile
#define BB 8192
#define CH 8       // timesteps per staged x chunk
#define NTH 512    // waves 0-3: layer0 engine; waves 4-7: layer1 engine

typedef float f32x4 __attribute__((ext_vector_type(4)));
typedef _Float16 f16x8 __attribute__((ext_vector_type(8)));

#define MFMA16F(A, B, C) __builtin_amdgcn_mfma_f32_16x16x32_f16((A), (B), (C), 0, 0, 0)

__device__ __forceinline__ f16x8 pack8(f32x4 a, f32x4 b) {
    f16x8 r;
#pragma unroll
    for (int e = 0; e < 4; ++e) { r[e] = (_Float16)a[e]; r[4 + e] = (_Float16)b[e]; }
    return r;
}

// fast activations: v_exp_f32 + v_rcp_f32, saturation-safe (inf/0 propagate correctly)
__device__ __forceinline__ float sigf(float v) {
    return __builtin_amdgcn_rcpf(1.0f + __builtin_amdgcn_exp2f(v * -1.44269504f));
}
__device__ __forceinline__ float thf(float v) {
    return fmaf(-2.0f, __builtin_amdgcn_rcpf(__builtin_amdgcn_exp2f(v * 2.88539008f) + 1.0f), 1.0f);
}

// cell update (4 units, 1 sample) + fp16 writeback of h to LDS
__device__ __forceinline__ void cell_update(const f32x4& gi, const f32x4& gf,
                                            const f32x4& gg, const f32x4& go,
                                            f32x4& cst, _Float16* dst) {
    f32x4 hv;
#pragma unroll
    for (int r = 0; r < 4; ++r) {
        const float iv = sigf(gi[r]), fv = sigf(gf[r]);
        const float gv = thf(gg[r]),  ov = sigf(go[r]);
        cst[r] = fv * cst[r] + iv * gv;
        hv[r] = ov * thf(cst[r]);
    }
    unsigned d0, d1;
    asm("v_cvt_pkrtz_f16_f32 %0, %1, %2" : "=v"(d0) : "v"(hv[0]), "v"(hv[1]));
    asm("v_cvt_pkrtz_f16_f32 %0, %1, %2" : "=v"(d1) : "v"(hv[2]), "v"(hv[3]));
    *(uint2*)dst = make_uint2(d0, d1);
}

__global__ __launch_bounds__(NTH, 4)
void weather_lstm_mfma(const float* __restrict__ x,
                       const float* __restrict__ w_ih0, const float* __restrict__ w_hh0,
                       const float* __restrict__ b_ih0, const float* __restrict__ b_hh0,
                       const float* __restrict__ w_ih1, const float* __restrict__ w_hh1,
                       const float* __restrict__ b_ih1, const float* __restrict__ b_hh1,
                       const float* __restrict__ fc_w, const float* __restrict__ fc_b,
                       float* __restrict__ out)
{
    __shared__ f16x8 xs[2][CH][NS];                           // 4 KB
    __shared__ __align__(16) _Float16 h1[2][NS][72];          // 4.6 KB (144B rows)
    __shared__ __align__(16) _Float16 h2[2][NS][72];          // 4.6 KB

    const int tid  = threadIdx.x;
    const int wv   = tid >> 6;       // 0..7
    const int q    = wv & 3;         // unit group within the engine
    const int lane = tid & 63;
    const int col  = lane & 15;      // weight row within tile / sample
    const int kg   = lane >> 4;      // k-group
    const int s0   = blockIdx.x * NS;
    const int ub   = 16 * q + 4 * kg;

    // ---------------- init: zero h (both parities), stage x chunk 0 ----------------
    for (int i = tid; i < 2 * NS * 72; i += NTH) {
        ((short*)h1)[i] = 0; ((short*)h2)[i] = 0;
    }
    if (tid < CH * NS) {             // 128 threads
        const int tloc = tid >> 4, ss = tid & 15;
        const float* px = x + ((size_t)(s0 + ss) * TT + tloc) * DD;
        f32x4 a, b;
        a[0] = px[0]; a[1] = px[1]; a[2] = px[2]; a[3] = px[3];
        b[0] = px[4]; b[1] = px[5]; b[2] = px[6]; b[3] = 1.0f;   // bias slot
        xs[0][tloc][ss] = pack8(a, b);
    }
    __syncthreads();

    const f16x8 z8 = {0, 0, 0, 0, 0, 0, 0, 0};
    const f32x4 zz = {0, 0, 0, 0};

    if (wv < 4) {
        // ==================== LAYER-0 ENGINE (waves 0-3) ====================
        // single-fp16 weights (RTNE): W0 = w_hh0 (K=64), WX = w_ih0 + bias0 in k-slot 7
        f16x8 W0[4][2], WX[4];
#pragma unroll
        for (int t4 = 0; t4 < 4; ++t4) {
            const int row = 64 * t4 + 16 * q + col;
#pragma unroll
            for (int kf = 0; kf < 2; ++kf) {
                const float* p = w_hh0 + (size_t)row * HH + 32 * kf + 8 * kg;
                W0[t4][kf] = pack8(*(const f32x4*)p, *(const f32x4*)(p + 4));
            }
            f32x4 a = {0, 0, 0, 0}, b = {0, 0, 0, 0};
            if (kg == 0) {
                const float* p = w_ih0 + (size_t)row * DD;
                a[0] = p[0]; a[1] = p[1]; a[2] = p[2]; a[3] = p[3];
                b[0] = p[4]; b[1] = p[5]; b[2] = p[6];
                b[3] = b_ih0[row] + b_hh0[row];     // bias0 rides k-slot 7
            }
            WX[t4] = pack8(a, b);
        }
        f32x4 c1 = {0, 0, 0, 0};

#pragma unroll 1
        for (int k = 0; k <= TT + 1; ++k) {
            f32x4 aA[4];
            // ---------- Segment A: L0 MFMA for step k ----------
            if (k < TT) {
                if (tid < CH * NS && (k & 7) == 0 && k + CH < TT) {   // refill next x chunk
                    const int tloc = tid >> 4, ss = tid & 15;
                    const int tg = k + CH + tloc;
                    const float* px = x + ((size_t)(s0 + ss) * TT + tg) * DD;
                    f32x4 a, b;
                    a[0] = px[0]; a[1] = px[1]; a[2] = px[2]; a[3] = px[3];
                    b[0] = px[4]; b[1] = px[5]; b[2] = px[6]; b[3] = 1.0f;
                    const int nb = ((k >> 3) & 1) ^ 1;
                    xs[nb][tloc][ss] = pack8(a, b);
                }
                const int cb = (k >> 3) & 1, tt = k & 7;
                const int rp = (k - 1) & 1;             // h1(k-1) parity

                __builtin_amdgcn_s_setprio(1);
                f16x8 ax = z8;
                if (kg == 0) ax = xs[cb][tt][col];
                aA[0] = MFMA16F(WX[0], ax, zz);
                aA[1] = MFMA16F(WX[1], ax, zz);
                aA[2] = MFMA16F(WX[2], ax, zz);
                aA[3] = MFMA16F(WX[3], ax, zz);
#pragma unroll
                for (int kf = 0; kf < 2; ++kf) {
                    const f16x8 dh = *(const f16x8*)&h1[rp][col][32 * kf + 8 * kg];
                    aA[0] = MFMA16F(W0[0][kf], dh, aA[0]);
                    aA[1] = MFMA16F(W0[1][kf], dh, aA[1]);
                    aA[2] = MFMA16F(W0[2][kf], dh, aA[2]);
                    aA[3] = MFMA16F(W0[3][kf], dh, aA[3]);
                }
                __builtin_amdgcn_s_setprio(0);
            }
            __syncthreads();   // B1
            // ---------- Segment B: L0 cell update for step k ----------
            if (k < TT) {
                const int wp = k & 1;
                cell_update(aA[0], aA[1], aA[2], aA[3], c1, &h1[wp][col][ub]);
            }
            __syncthreads();   // B2
        }
    } else {
        // ==================== LAYER-1 ENGINE (waves 4-7) ====================
        f16x8 W1[4][4];   // kf 0..1: w_ih1 (h1 input); kf 2..3: w_hh1 (h2 input)
        f32x4 bias1[4];
#pragma unroll
        for (int t4 = 0; t4 < 4; ++t4) {
            const int row = 64 * t4 + 16 * q + col;
            const int rr  = 64 * t4 + 16 * q + 4 * kg;
            bias1[t4] = *(const f32x4*)(b_ih1 + rr) + *(const f32x4*)(b_hh1 + rr);
#pragma unroll
            for (int kf = 0; kf < 4; ++kf) {
                const float* base = (kf < 2) ? (w_ih1 + (size_t)row * HH + 32 * kf)
                                             : (w_hh1 + (size_t)row * HH + 32 * (kf - 2));
                const float* p = base + 8 * kg;
                W1[t4][kf] = pack8(*(const f32x4*)p, *(const f32x4*)(p + 4));
            }
        }
        f32x4 c2 = {0, 0, 0, 0};
        f32x4 aB[4];

#pragma unroll 1
        for (int k = 0; k <= TT + 1; ++k) {
            // ---------- Segment A: L1 cell update for step k-2 ----------
            if (k >= 2) {
                const int wp = k & 1;                   // (k-2)&1
                cell_update(aB[0], aB[1], aB[2], aB[3], c2, &h2[wp][col][ub]);
            }
            __syncthreads();   // B1
            // ---------- Segment B: L1 MFMA for step k-1 (C-init = bias) ----------
            if (k >= 1 && k <= TT) {
                const int rp1 = (k - 1) & 1;            // h1(k-1) parity
                const int rp2 = k & 1;                  // h2(k-2) parity
                __builtin_amdgcn_s_setprio(1);
                {
                    const f16x8 dh = *(const f16x8*)&h1[rp1][col][8 * kg];
                    aB[0] = MFMA16F(W1[0][0], dh, bias1[0]);
                    aB[1] = MFMA16F(W1[1][0], dh, bias1[1]);
                    aB[2] = MFMA16F(W1[2][0], dh, bias1[2]);
                    aB[3] = MFMA16F(W1[3][0], dh, bias1[3]);
                }
                {
                    const f16x8 dh = *(const f16x8*)&h1[rp1][col][32 + 8 * kg];
                    aB[0] = MFMA16F(W1[0][1], dh, aB[0]);
                    aB[1] = MFMA16F(W1[1][1], dh, aB[1]);
                    aB[2] = MFMA16F(W1[2][1], dh, aB[2]);
                    aB[3] = MFMA16F(W1[3][1], dh, aB[3]);
                }
#pragma unroll
                for (int kf = 0; kf < 2; ++kf) {        // h2(k-2) input
                    const f16x8 eh = *(const f16x8*)&h2[rp2][col][32 * kf + 8 * kg];
                    aB[0] = MFMA16F(W1[0][kf + 2], eh, aB[0]);
                    aB[1] = MFMA16F(W1[1][kf + 2], eh, aB[1]);
                    aB[2] = MFMA16F(W1[2][kf + 2], eh, aB[2]);
                    aB[3] = MFMA16F(W1[3][kf + 2], eh, aB[3]);
                }
                __builtin_amdgcn_s_setprio(0);
            }
            __syncthreads();   // B2
        }
    }

    // ---------------- FC head on final h2 = h2(TT-1), parity 1 ----------------
    if (tid < NS * 4) {
        const int s = tid >> 2, k = tid & 3;
        float a = fc_b[k];
#pragma unroll
        for (int j = 0; j < HH; ++j)
            a = fmaf((float)h2[1][s][j], fc_w[k * HH + j], a);
        out[(size_t)(s0 + s) * 4 + k] = a;
    }
}

extern "C" void kernel_launch(void* const* d_in, const int* in_sizes, int n_in,
                              void* d_out, int out_size, void* d_ws, size_t ws_size,
                              hipStream_t stream) {
    const float* x     = (const float*)d_in[0];
    const float* w_ih0 = (const float*)d_in[1];
    const float* w_hh0 = (const float*)d_in[2];
    const float* b_ih0 = (const float*)d_in[3];
    const float* b_hh0 = (const float*)d_in[4];
    const float* w_ih1 = (const float*)d_in[5];
    const float* w_hh1 = (const float*)d_in[6];
    const float* b_ih1 = (const float*)d_in[7];
    const float* b_hh1 = (const float*)d_in[8];
    const float* fc_w  = (const float*)d_in[9];
    const float* fc_b  = (const float*)d_in[10];
    float* out = (float*)d_out;

    dim3 grid(BB / NS), block(NTH);
    weather_lstm_mfma<<<grid, block, 0, stream>>>(
        x, w_ih0, w_hh0, b_ih0, b_hh0,
        w_ih1, w_hh1, b_ih1, b_hh1, fc_w, fc_b, out);
}

// Round 13
// 238.553 us; speedup vs baseline: 1.3933x; 1.0477x over previous
//
#include <hip/hip_runtime.h>

#define TT 168
#define HH 64
#define DD 7
#define NS 16      // samples per block: ONE N=16 MFMA sample-tile
#define BB 8192
#define CH 8       // timesteps per staged x chunk
#define NTH 512    // waves 0-3: layer0 engine; waves 4-7: layer1 engine

typedef float f32x4 __attribute__((ext_vector_type(4)));
typedef _Float16 f16x8 __attribute__((ext_vector_type(8)));

#define MFMA16F(A, B, C) __builtin_amdgcn_mfma_f32_16x16x32_f16((A), (B), (C), 0, 0, 0)

__device__ __forceinline__ f16x8 pack8(f32x4 a, f32x4 b) {
    f16x8 r;
#pragma unroll
    for (int e = 0; e < 4; ++e) { r[e] = (_Float16)a[e]; r[4 + e] = (_Float16)b[e]; }
    return r;
}

// cell update (4 units, 1 sample) with PRE-SCALED gate args:
//   si,sf,so = -log2e * (raw gate);  sg = -2log2e * (raw gate)   [folded into W,b]
//   sig(x)  = rcp(1+exp2(s))
//   i*g     = (1-ug) * rcp((1+ui)(1+ug))          [shared rcp; clamp sg]
//   o*tanh  = (1-uc) * rcp((1+uo)(1+uc))          [shared rcp; clamp sc]
// Saturation exactness: ui=inf -> ig=0 (=i*g); uc=2^80 -> h=-sig(o) (=tanh->-1).
__device__ __forceinline__ void cell_update(const f32x4& si, const f32x4& sf,
                                            const f32x4& sg, const f32x4& so,
                                            f32x4& cst, _Float16* dst) {
    f32x4 hv;
#pragma unroll
    for (int r = 0; r < 4; ++r) {
        const float uf = __builtin_amdgcn_exp2f(sf[r]);
        const float fv = __builtin_amdgcn_rcpf(1.0f + uf);
        const float ui = __builtin_amdgcn_exp2f(si[r]);
        const float ug = __builtin_amdgcn_exp2f(fminf(sg[r], 80.0f));
        const float R1 = __builtin_amdgcn_rcpf((1.0f + ui) * (1.0f + ug));
        const float ig = (1.0f - ug) * R1;
        cst[r] = fv * cst[r] + ig;
        const float uo = __builtin_amdgcn_exp2f(so[r]);
        const float uc = __builtin_amdgcn_exp2f(fminf(cst[r] * -2.88539008f, 80.0f));
        const float R2 = __builtin_amdgcn_rcpf((1.0f + uo) * (1.0f + uc));
        hv[r] = (1.0f - uc) * R2;
    }
    unsigned d0, d1;
    asm("v_cvt_pkrtz_f16_f32 %0, %1, %2" : "=v"(d0) : "v"(hv[0]), "v"(hv[1]));
    asm("v_cvt_pkrtz_f16_f32 %0, %1, %2" : "=v"(d1) : "v"(hv[2]), "v"(hv[3]));
    *(uint2*)dst = make_uint2(d0, d1);
}

__global__ __launch_bounds__(NTH, 4)
void weather_lstm_mfma(const float* __restrict__ x,
                       const float* __restrict__ w_ih0, const float* __restrict__ w_hh0,
                       const float* __restrict__ b_ih0, const float* __restrict__ b_hh0,
                       const float* __restrict__ w_ih1, const float* __restrict__ w_hh1,
                       const float* __restrict__ b_ih1, const float* __restrict__ b_hh1,
                       const float* __restrict__ fc_w, const float* __restrict__ fc_b,
                       float* __restrict__ out)
{
    __shared__ f16x8 xs[2][CH][NS];                           // 4 KB
    __shared__ __align__(16) _Float16 h1[2][NS][72];          // 4.6 KB (144B rows)
    __shared__ __align__(16) _Float16 h2[2][NS][72];          // 4.6 KB

    const int tid  = threadIdx.x;
    const int wv   = tid >> 6;       // 0..7
    const int q    = wv & 3;         // unit group within the engine
    const int lane = tid & 63;
    const int col  = lane & 15;      // weight row within tile / sample
    const int kg   = lane >> 4;      // k-group
    const int s0   = blockIdx.x * NS;
    const int ub   = 16 * q + 4 * kg;

    // ---------------- init: zero h (both parities), stage x chunk 0 ----------------
    for (int i = tid; i < 2 * NS * 72; i += NTH) {
        ((short*)h1)[i] = 0; ((short*)h2)[i] = 0;
    }
    if (tid < CH * NS) {             // 128 threads
        const int tloc = tid >> 4, ss = tid & 15;
        const float* px = x + ((size_t)(s0 + ss) * TT + tloc) * DD;
        f32x4 a, b;
        a[0] = px[0]; a[1] = px[1]; a[2] = px[2]; a[3] = px[3];
        b[0] = px[4]; b[1] = px[5]; b[2] = px[6]; b[3] = 1.0f;   // bias slot
        xs[0][tloc][ss] = pack8(a, b);
    }
    __syncthreads();

    const f16x8 z8 = {0, 0, 0, 0, 0, 0, 0, 0};
    const f32x4 zz = {0, 0, 0, 0};

    if (wv < 4) {
        // ==================== LAYER-0 ENGINE (waves 0-3) ====================
        // Pre-scaled single-fp16 weights: gate rows i,f,o x(-log2e), g x(-2log2e)
        f16x8 W0[4][2], WX[4];
#pragma unroll
        for (int t4 = 0; t4 < 4; ++t4) {
            const float sc = (t4 == 2) ? -2.88539008f : -1.44269504f;
            const int row = 64 * t4 + 16 * q + col;
#pragma unroll
            for (int kf = 0; kf < 2; ++kf) {
                const float* p = w_hh0 + (size_t)row * HH + 32 * kf + 8 * kg;
                W0[t4][kf] = pack8(*(const f32x4*)p * sc, *(const f32x4*)(p + 4) * sc);
            }
            f32x4 a = {0, 0, 0, 0}, b = {0, 0, 0, 0};
            if (kg == 0) {
                const float* p = w_ih0 + (size_t)row * DD;
                a[0] = p[0]; a[1] = p[1]; a[2] = p[2]; a[3] = p[3];
                b[0] = p[4]; b[1] = p[5]; b[2] = p[6];
                b[3] = b_ih0[row] + b_hh0[row];     // bias0 rides k-slot 7
            }
            WX[t4] = pack8(a * sc, b * sc);
        }
        f32x4 c1 = {0, 0, 0, 0};

#pragma unroll 1
        for (int k = 0; k <= TT; ++k) {
            if (k < TT) {
                if (tid < CH * NS && (k & 7) == 0 && k + CH < TT) {   // refill next x chunk
                    const int tloc = tid >> 4, ss = tid & 15;
                    const int tg = k + CH + tloc;
                    const float* px = x + ((size_t)(s0 + ss) * TT + tg) * DD;
                    f32x4 a, b;
                    a[0] = px[0]; a[1] = px[1]; a[2] = px[2]; a[3] = px[3];
                    b[0] = px[4]; b[1] = px[5]; b[2] = px[6]; b[3] = 1.0f;
                    const int nb = ((k >> 3) & 1) ^ 1;
                    xs[nb][tloc][ss] = pack8(a, b);
                }
                const int cb = (k >> 3) & 1, tt = k & 7;
                const int rp = (k - 1) & 1;             // h1(k-1) parity

                f32x4 aA[4];
                __builtin_amdgcn_s_setprio(1);
                f16x8 ax = z8;
                if (kg == 0) ax = xs[cb][tt][col];
                aA[0] = MFMA16F(WX[0], ax, zz);
                aA[1] = MFMA16F(WX[1], ax, zz);
                aA[2] = MFMA16F(WX[2], ax, zz);
                aA[3] = MFMA16F(WX[3], ax, zz);
#pragma unroll
                for (int kf = 0; kf < 2; ++kf) {
                    const f16x8 dh = *(const f16x8*)&h1[rp][col][32 * kf + 8 * kg];
                    aA[0] = MFMA16F(W0[0][kf], dh, aA[0]);
                    aA[1] = MFMA16F(W0[1][kf], dh, aA[1]);
                    aA[2] = MFMA16F(W0[2][kf], dh, aA[2]);
                    aA[3] = MFMA16F(W0[3][kf], dh, aA[3]);
                }
                __builtin_amdgcn_s_setprio(0);
                // cell(k) -> h1[k&1]  (readers of h1[rp] are pre-barrier; wp != rp)
                cell_update(aA[0], aA[1], aA[2], aA[3], c1, &h1[k & 1][col][ub]);
            }
            __syncthreads();
        }
    } else {
        // ==================== LAYER-1 ENGINE (waves 4-7) ====================
        f16x8 W1[4][4];   // kf 0..1: w_ih1 (h1 input); kf 2..3: w_hh1 (h2 input)
        f32x4 bias1[4];
#pragma unroll
        for (int t4 = 0; t4 < 4; ++t4) {
            const float sc = (t4 == 2) ? -2.88539008f : -1.44269504f;
            const int row = 64 * t4 + 16 * q + col;
            const int rr  = 64 * t4 + 16 * q + 4 * kg;
            bias1[t4] = (*(const f32x4*)(b_ih1 + rr) + *(const f32x4*)(b_hh1 + rr)) * sc;
#pragma unroll
            for (int kf = 0; kf < 4; ++kf) {
                const float* base = (kf < 2) ? (w_ih1 + (size_t)row * HH + 32 * kf)
                                             : (w_hh1 + (size_t)row * HH + 32 * (kf - 2));
                const float* p = base + 8 * kg;
                W1[t4][kf] = pack8(*(const f32x4*)p * sc, *(const f32x4*)(p + 4) * sc);
            }
        }
        f32x4 c2 = {0, 0, 0, 0};

#pragma unroll 1
        for (int k = 0; k <= TT; ++k) {
            if (k >= 1) {
                // MFMA for step k-1: h1(k-1) slot (k-1)&1, h2(k-2) slot k&1
                const int rp1 = (k - 1) & 1;
                const int rp2 = k & 1;
                f32x4 aB[4];
                __builtin_amdgcn_s_setprio(1);
                {
                    const f16x8 dh = *(const f16x8*)&h1[rp1][col][8 * kg];
                    aB[0] = MFMA16F(W1[0][0], dh, bias1[0]);
                    aB[1] = MFMA16F(W1[1][0], dh, bias1[1]);
                    aB[2] = MFMA16F(W1[2][0], dh, bias1[2]);
                    aB[3] = MFMA16F(W1[3][0], dh, bias1[3]);
                }
                {
                    const f16x8 dh = *(const f16x8*)&h1[rp1][col][32 + 8 * kg];
                    aB[0] = MFMA16F(W1[0][1], dh, aB[0]);
                    aB[1] = MFMA16F(W1[1][1], dh, aB[1]);
                    aB[2] = MFMA16F(W1[2][1], dh, aB[2]);
                    aB[3] = MFMA16F(W1[3][1], dh, aB[3]);
                }
#pragma unroll
                for (int kf = 0; kf < 2; ++kf) {        // h2(k-2) input
                    const f16x8 eh = *(const f16x8*)&h2[rp2][col][32 * kf + 8 * kg];
                    aB[0] = MFMA16F(W1[0][kf + 2], eh, aB[0]);
                    aB[1] = MFMA16F(W1[1][kf + 2], eh, aB[1]);
                    aB[2] = MFMA16F(W1[2][kf + 2], eh, aB[2]);
                    aB[3] = MFMA16F(W1[3][kf + 2], eh, aB[3]);
                }
                __builtin_amdgcn_s_setprio(0);
                // cell(k-1) -> h2[(k-1)&1]  (readers used slot k&1 this region)
                cell_update(aB[0], aB[1], aB[2], aB[3], c2, &h2[(k - 1) & 1][col][ub]);
            }
            __syncthreads();
        }
    }

    // ---------------- FC head on final h2 = h2(TT-1), slot (TT-1)&1 = 1 ----------------
    if (tid < NS * 4) {
        const int s = tid >> 2, k = tid & 3;
        float a = fc_b[k];
#pragma unroll
        for (int j = 0; j < HH; ++j)
            a = fmaf((float)h2[1][s][j], fc_w[k * HH + j], a);
        out[(size_t)(s0 + s) * 4 + k] = a;
    }
}

extern "C" void kernel_launch(void* const* d_in, const int* in_sizes, int n_in,
                              void* d_out, int out_size, void* d_ws, size_t ws_size,
                              hipStream_t stream) {
    const float* x     = (const float*)d_in[0];
    const float* w_ih0 = (const float*)d_in[1];
    const float* w_hh0 = (const float*)d_in[2];
    const float* b_ih0 = (const float*)d_in[3];
    const float* b_hh0 = (const float*)d_in[4];
    const float* w_ih1 = (const float*)d_in[5];
    const float* w_hh1 = (const float*)d_in[6];
    const float* b_ih1 = (const float*)d_in[7];
    const float* b_hh1 = (const float*)d_in[8];
    const float* fc_w  = (const float*)d_in[9];
    const float* fc_b  = (const float*)d_in[10];
    float* out = (float*)d_out;

    dim3 grid(BB / NS), block(NTH);
    weather_lstm_mfma<<<grid, block, 0, stream>>>(
        x, w_ih0, w_hh0, b_ih0, b_hh0,
        w_ih1, w_hh1, b_ih1, b_hh1, fc_w, fc_b, out);
}

// Round 14
// 228.219 us; speedup vs baseline: 1.4564x; 1.0453x over previous
//
#include <hip/hip_runtime.h>

#define TT 168
#define HH 64
#define DD 7
#define NS 16      // samples per block: ONE N=16 MFMA sample-tile
#define BB 8192
#define CH 8       // timesteps per staged x chunk
#define NTH 512    // waves 0-3: layer0 engine; waves 4-7: layer1 engine

typedef float f32x4 __attribute__((ext_vector_type(4)));
typedef _Float16 f16x8 __attribute__((ext_vector_type(8)));

#define MFMA16F(A, B, C) __builtin_amdgcn_mfma_f32_16x16x32_f16((A), (B), (C), 0, 0, 0)

__device__ __forceinline__ f16x8 pack8(f32x4 a, f32x4 b) {
    f16x8 r;
#pragma unroll
    for (int e = 0; e < 4; ++e) { r[e] = (_Float16)a[e]; r[4 + e] = (_Float16)b[e]; }
    return r;
}

// cell update (4 units, 1 sample) with PRE-SCALED gate args (identical to r13):
//   si,sf,so = -log2e * (raw gate);  sg = -2log2e * (raw gate)   [folded into W,b]
__device__ __forceinline__ void cell_update(const f32x4& si, const f32x4& sf,
                                            const f32x4& sg, const f32x4& so,
                                            f32x4& cst, _Float16* dst) {
    f32x4 hv;
#pragma unroll
    for (int r = 0; r < 4; ++r) {
        const float uf = __builtin_amdgcn_exp2f(sf[r]);
        const float fv = __builtin_amdgcn_rcpf(1.0f + uf);
        const float ui = __builtin_amdgcn_exp2f(si[r]);
        const float ug = __builtin_amdgcn_exp2f(fminf(sg[r], 80.0f));
        const float R1 = __builtin_amdgcn_rcpf((1.0f + ui) * (1.0f + ug));
        const float ig = (1.0f - ug) * R1;
        cst[r] = fv * cst[r] + ig;
        const float uo = __builtin_amdgcn_exp2f(so[r]);
        const float uc = __builtin_amdgcn_exp2f(fminf(cst[r] * -2.88539008f, 80.0f));
        const float R2 = __builtin_amdgcn_rcpf((1.0f + uo) * (1.0f + uc));
        hv[r] = (1.0f - uc) * R2;
    }
    unsigned d0, d1;
    asm("v_cvt_pkrtz_f16_f32 %0, %1, %2" : "=v"(d0) : "v"(hv[0]), "v"(hv[1]));
    asm("v_cvt_pkrtz_f16_f32 %0, %1, %2" : "=v"(d1) : "v"(hv[2]), "v"(hv[3]));
    *(uint2*)dst = make_uint2(d0, d1);
}

__global__ __launch_bounds__(NTH, 4)
void weather_lstm_mfma(const float* __restrict__ x,
                       const float* __restrict__ w_ih0, const float* __restrict__ w_hh0,
                       const float* __restrict__ b_ih0, const float* __restrict__ b_hh0,
                       const float* __restrict__ w_ih1, const float* __restrict__ w_hh1,
                       const float* __restrict__ b_ih1, const float* __restrict__ b_hh1,
                       const float* __restrict__ fc_w, const float* __restrict__ fc_b,
                       float* __restrict__ out)
{
    __shared__ f16x8 xs[2][CH][NS];                           // 4 KB
    __shared__ __align__(16) _Float16 h1[2][NS][72];          // 4.6 KB (144B rows)
    __shared__ __align__(16) _Float16 h2[2][NS][72];          // 4.6 KB

    const int tid  = threadIdx.x;
    const int wv   = tid >> 6;       // 0..7
    const int q    = wv & 3;         // unit group within the engine
    const int lane = tid & 63;
    const int col  = lane & 15;      // weight row within tile / sample
    const int kg   = lane >> 4;      // k-group
    const int s0   = blockIdx.x * NS;
    const int ub   = 16 * q + 4 * kg;

    // ---------------- init: zero h (both parities), stage x chunk 0 ----------------
    for (int i = tid; i < 2 * NS * 72; i += NTH) {
        ((short*)h1)[i] = 0; ((short*)h2)[i] = 0;
    }
    if (tid < CH * NS) {             // 128 threads
        const int tloc = tid >> 4, ss = tid & 15;
        const float* px = x + ((size_t)(s0 + ss) * TT + tloc) * DD;
        f32x4 a, b;
        a[0] = px[0]; a[1] = px[1]; a[2] = px[2]; a[3] = px[3];
        b[0] = px[4]; b[1] = px[5]; b[2] = px[6]; b[3] = 1.0f;   // bias slot
        xs[0][tloc][ss] = pack8(a, b);
    }
    __syncthreads();

    const f16x8 z8 = {0, 0, 0, 0, 0, 0, 0, 0};
    const f32x4 zz = {0, 0, 0, 0};

    if (wv < 4) {
        // ==================== LAYER-0 ENGINE (waves 0-3) ====================
        // Pre-scaled single-fp16 weights: gate rows i,f,o x(-log2e), g x(-2log2e)
        f16x8 W0[4][2], WX[4];
#pragma unroll
        for (int t4 = 0; t4 < 4; ++t4) {
            const float sc = (t4 == 2) ? -2.88539008f : -1.44269504f;
            const int row = 64 * t4 + 16 * q + col;
#pragma unroll
            for (int kf = 0; kf < 2; ++kf) {
                const float* p = w_hh0 + (size_t)row * HH + 32 * kf + 8 * kg;
                W0[t4][kf] = pack8(*(const f32x4*)p * sc, *(const f32x4*)(p + 4) * sc);
            }
            f32x4 a = {0, 0, 0, 0}, b = {0, 0, 0, 0};
            if (kg == 0) {
                const float* p = w_ih0 + (size_t)row * DD;
                a[0] = p[0]; a[1] = p[1]; a[2] = p[2]; a[3] = p[3];
                b[0] = p[4]; b[1] = p[5]; b[2] = p[6];
                b[3] = b_ih0[row] + b_hh0[row];     // bias0 rides k-slot 7
            }
            WX[t4] = pack8(a * sc, b * sc);
        }
        f32x4 c1 = {0, 0, 0, 0};

        // loop-invariant pointers (parities are compile-time per sub-step)
        const f16x8* xbase = &xs[0][0][0];
        const _Float16* r0a = &h1[0][col][8 * kg];
        const _Float16* r0b = &h1[0][col][32 + 8 * kg];
        const _Float16* r1a = &h1[1][col][8 * kg];
        const _Float16* r1b = &h1[1][col][32 + 8 * kg];
        _Float16* wp0 = &h1[0][col][ub];
        _Float16* wp1 = &h1[1][col][ub];

        auto l0_step = [&](const f16x8* xp, const _Float16* ra, const _Float16* rb,
                           _Float16* wr) {
            f32x4 a0, a1, a2, a3;
            __builtin_amdgcn_s_setprio(1);
            f16x8 ax = z8;
            if (kg == 0) ax = *xp;
            a0 = MFMA16F(WX[0], ax, zz);
            a1 = MFMA16F(WX[1], ax, zz);
            a2 = MFMA16F(WX[2], ax, zz);
            a3 = MFMA16F(WX[3], ax, zz);
            f16x8 dh = *(const f16x8*)ra;
            a0 = MFMA16F(W0[0][0], dh, a0);
            a1 = MFMA16F(W0[1][0], dh, a1);
            a2 = MFMA16F(W0[2][0], dh, a2);
            a3 = MFMA16F(W0[3][0], dh, a3);
            dh = *(const f16x8*)rb;
            a0 = MFMA16F(W0[0][1], dh, a0);
            a1 = MFMA16F(W0[1][1], dh, a1);
            a2 = MFMA16F(W0[2][1], dh, a2);
            a3 = MFMA16F(W0[3][1], dh, a3);
            __builtin_amdgcn_s_setprio(0);
            cell_update(a0, a1, a2, a3, c1, wr);
        };
        auto refill = [&](int kref) {          // loads chunk starting at kref+CH
            if (tid < CH * NS) {
                const int tloc = tid >> 4, ss = tid & 15;
                const int tg = kref + CH + tloc;
                const float* px = x + ((size_t)(s0 + ss) * TT + tg) * DD;
                f32x4 a, b;
                a[0] = px[0]; a[1] = px[1]; a[2] = px[2]; a[3] = px[3];
                b[0] = px[4]; b[1] = px[5]; b[2] = px[6]; b[3] = 1.0f;
                const int nb = ((kref >> 3) & 1) ^ 1;
                xs[nb][tloc][ss] = pack8(a, b);
            }
        };

        // ---- peel k=0 (reads h1[1]=0, writes h1[0]) and k=1 ----
        refill(0);
        l0_step(xbase + col, r1a, r1b, wp0);
        __syncthreads();
        l0_step(xbase + NS + col, r0a, r0b, wp1);
        __syncthreads();

#pragma unroll 1
        for (int j = 1; j < 84; ++j) {
            const f16x8* xpA = xbase + ((2 * j) & 15) * NS + col;
            if ((j & 3) == 0 && j < 80) refill(2 * j);
            l0_step(xpA, r1a, r1b, wp0);        // k=2j   : read h1[1], write h1[0]
            __syncthreads();
            l0_step(xpA + NS, r0a, r0b, wp1);   // k=2j+1 : read h1[0], write h1[1]
            __syncthreads();
        }
        __syncthreads();   // epilogue region k=168 (L0 idle)
    } else {
        // ==================== LAYER-1 ENGINE (waves 4-7) ====================
        f16x8 W1[4][4];   // kf 0..1: w_ih1 (h1 input); kf 2..3: w_hh1 (h2 input)
        f32x4 bias1[4];
#pragma unroll
        for (int t4 = 0; t4 < 4; ++t4) {
            const float sc = (t4 == 2) ? -2.88539008f : -1.44269504f;
            const int row = 64 * t4 + 16 * q + col;
            const int rr  = 64 * t4 + 16 * q + 4 * kg;
            bias1[t4] = (*(const f32x4*)(b_ih1 + rr) + *(const f32x4*)(b_hh1 + rr)) * sc;
#pragma unroll
            for (int kf = 0; kf < 4; ++kf) {
                const float* base = (kf < 2) ? (w_ih1 + (size_t)row * HH + 32 * kf)
                                             : (w_hh1 + (size_t)row * HH + 32 * (kf - 2));
                const float* p = base + 8 * kg;
                W1[t4][kf] = pack8(*(const f32x4*)p * sc, *(const f32x4*)(p + 4) * sc);
            }
        }
        f32x4 c2 = {0, 0, 0, 0};

        const _Float16* p1a0 = &h1[0][col][8 * kg];
        const _Float16* p1b0 = &h1[0][col][32 + 8 * kg];
        const _Float16* p1a1 = &h1[1][col][8 * kg];
        const _Float16* p1b1 = &h1[1][col][32 + 8 * kg];
        const _Float16* p2a0 = &h2[0][col][8 * kg];
        const _Float16* p2b0 = &h2[0][col][32 + 8 * kg];
        const _Float16* p2a1 = &h2[1][col][8 * kg];
        const _Float16* p2b1 = &h2[1][col][32 + 8 * kg];
        _Float16* q0 = &h2[0][col][ub];
        _Float16* q1 = &h2[1][col][ub];

        auto l1_step = [&](const _Float16* ha, const _Float16* hb,
                           const _Float16* ea, const _Float16* eb, _Float16* wr) {
            f32x4 a0, a1, a2, a3;
            __builtin_amdgcn_s_setprio(1);
            f16x8 dh = *(const f16x8*)ha;
            a0 = MFMA16F(W1[0][0], dh, bias1[0]);
            a1 = MFMA16F(W1[1][0], dh, bias1[1]);
            a2 = MFMA16F(W1[2][0], dh, bias1[2]);
            a3 = MFMA16F(W1[3][0], dh, bias1[3]);
            dh = *(const f16x8*)hb;
            a0 = MFMA16F(W1[0][1], dh, a0);
            a1 = MFMA16F(W1[1][1], dh, a1);
            a2 = MFMA16F(W1[2][1], dh, a2);
            a3 = MFMA16F(W1[3][1], dh, a3);
            dh = *(const f16x8*)ea;
            a0 = MFMA16F(W1[0][2], dh, a0);
            a1 = MFMA16F(W1[1][2], dh, a1);
            a2 = MFMA16F(W1[2][2], dh, a2);
            a3 = MFMA16F(W1[3][2], dh, a3);
            dh = *(const f16x8*)eb;
            a0 = MFMA16F(W1[0][3], dh, a0);
            a1 = MFMA16F(W1[1][3], dh, a1);
            a2 = MFMA16F(W1[2][3], dh, a2);
            a3 = MFMA16F(W1[3][3], dh, a3);
            __builtin_amdgcn_s_setprio(0);
            cell_update(a0, a1, a2, a3, c2, wr);
        };

        // ---- peel k=0 (idle) and k=1 (reads h1[0], h2[1]=0, writes h2[0]) ----
        __syncthreads();
        l1_step(p1a0, p1b0, p2a1, p2b1, q0);
        __syncthreads();

#pragma unroll 1
        for (int j = 1; j < 84; ++j) {
            l1_step(p1a1, p1b1, p2a0, p2b0, q1);   // k=2j   : cell(k-1) -> h2[1]
            __syncthreads();
            l1_step(p1a0, p1b0, p2a1, p2b1, q0);   // k=2j+1 : cell(k-1) -> h2[0]
            __syncthreads();
        }
        // ---- epilogue k=168: cell(167) -> h2[1] ----
        l1_step(p1a1, p1b1, p2a0, p2b0, q1);
        __syncthreads();
    }

    // ---------------- FC head on final h2 = h2(TT-1), slot 1 ----------------
    if (tid < NS * 4) {
        const int s = tid >> 2, k = tid & 3;
        float a = fc_b[k];
#pragma unroll
        for (int j = 0; j < HH; ++j)
            a = fmaf((float)h2[1][s][j], fc_w[k * HH + j], a);
        out[(size_t)(s0 + s) * 4 + k] = a;
    }
}

extern "C" void kernel_launch(void* const* d_in, const int* in_sizes, int n_in,
                              void* d_out, int out_size, void* d_ws, size_t ws_size,
                              hipStream_t stream) {
    const float* x     = (const float*)d_in[0];
    const float* w_ih0 = (const float*)d_in[1];
    const float* w_hh0 = (const float*)d_in[2];
    const float* b_ih0 = (const float*)d_in[3];
    const float* b_hh0 = (const float*)d_in[4];
    const float* w_ih1 = (const float*)d_in[5];
    const float* w_hh1 = (const float*)d_in[6];
    const float* b_ih1 = (const float*)d_in[7];
    const float* b_hh1 = (const float*)d_in[8];
    const float* fc_w  = (const float*)d_in[9];
    const float* fc_b  = (const float*)d_in[10];
    float* out = (float*)d_out;

    dim3 grid(BB / NS), block(NTH);
    weather_lstm_mfma<<<grid, block, 0, stream>>>(
        x, w_ih0, w_hh0, b_ih0, b_hh0,
        w_ih1, w_hh1, b_ih1, b_hh1, fc_w, fc_b, out);
}

// Round 15
// 225.828 us; speedup vs baseline: 1.4718x; 1.0106x over previous
//
#include <hip/hip_runtime.h>

#define TT 168
#define HH 64
#define DD 7
#define NS 16      // samples per block: ONE N=16 MFMA sample-tile
#define BB 8192
#define CH 8       // timesteps per staged x chunk
#define NTH 512    // waves 0-3: layer0 engine; waves 4-7: layer1 engine

typedef float f32x2 __attribute__((ext_vector_type(2)));
typedef float f32x4 __attribute__((ext_vector_type(4)));
typedef _Float16 f16x8 __attribute__((ext_vector_type(8)));

#define MFMA16F(A, B, C) __builtin_amdgcn_mfma_f32_16x16x32_f16((A), (B), (C), 0, 0, 0)

__device__ __forceinline__ f16x8 pack8(f32x4 a, f32x4 b) {
    f16x8 r;
#pragma unroll
    for (int e = 0; e < 4; ++e) { r[e] = (_Float16)a[e]; r[4 + e] = (_Float16)b[e]; }
    return r;
}

__device__ __forceinline__ f32x2 exp2x2(f32x2 a) {
    return (f32x2){__builtin_amdgcn_exp2f(fminf(a.x, 40.0f)),
                   __builtin_amdgcn_exp2f(fminf(a.y, 40.0f))};
}
__device__ __forceinline__ f32x2 rcpx2(f32x2 a) {
    return (f32x2){__builtin_amdgcn_rcpf(a.x), __builtin_amdgcn_rcpf(a.y)};
}

// cell pair (2 units) on packed f32x2 math, PRE-SCALED args (folded into W,b):
//   si,sf,so = -log2e*raw; sg = -2log2e*raw; state cs = -2log2e*c
//   fv = pig*R1, igs = (2.885*ug-2.885)*opf*R1, R1 = rcp(pig*opf)
//   h  = (1-uc)*rcp((1+uo)(1+uc)),  uc = exp2(cs)
// All exp2 args clamped at 40 -> max product 2^120, every saturation path finite/exact.
__device__ __forceinline__ void cell_pair(f32x2 si, f32x2 sf, f32x2 sg, f32x2 so,
                                          f32x2& cs, unsigned& dpk) {
    const f32x2 one = {1.0f, 1.0f};
    const f32x2 ui  = exp2x2(si);
    const f32x2 uf  = exp2x2(sf);
    const f32x2 ug  = exp2x2(sg);
    const f32x2 opf = one + uf;
    const f32x2 pig = (one + ui) * (one + ug);
    const f32x2 R1  = rcpx2(pig * opf);
    const f32x2 fv  = pig * R1;
    const f32x2 igs = (ug * 2.88539008f - (f32x2){2.88539008f, 2.88539008f}) * (opf * R1);
    cs = fv * cs + igs;
    const f32x2 uo = exp2x2(so);
    const f32x2 uc = exp2x2(cs);
    const f32x2 R2 = rcpx2((one + uo) * (one + uc));
    const f32x2 hv = (one - uc) * R2;
    asm("v_cvt_pkrtz_f16_f32 %0, %1, %2" : "=v"(dpk) : "v"(hv.x), "v"(hv.y));
}

__device__ __forceinline__ void cell_update(const f32x4& gi, const f32x4& gf,
                                            const f32x4& gg, const f32x4& go,
                                            f32x4& cs, _Float16* dst) {
    f32x2 csA = {cs[0], cs[1]}, csB = {cs[2], cs[3]};
    unsigned d0, d1;
    cell_pair((f32x2){gi[0], gi[1]}, (f32x2){gf[0], gf[1]},
              (f32x2){gg[0], gg[1]}, (f32x2){go[0], go[1]}, csA, d0);
    cell_pair((f32x2){gi[2], gi[3]}, (f32x2){gf[2], gf[3]},
              (f32x2){gg[2], gg[3]}, (f32x2){go[2], go[3]}, csB, d1);
    cs[0] = csA.x; cs[1] = csA.y; cs[2] = csB.x; cs[3] = csB.y;
    *(uint2*)dst = make_uint2(d0, d1);
}

__global__ __launch_bounds__(NTH, 4)
void weather_lstm_mfma(const float* __restrict__ x,
                       const float* __restrict__ w_ih0, const float* __restrict__ w_hh0,
                       const float* __restrict__ b_ih0, const float* __restrict__ b_hh0,
                       const float* __restrict__ w_ih1, const float* __restrict__ w_hh1,
                       const float* __restrict__ b_ih1, const float* __restrict__ b_hh1,
                       const float* __restrict__ fc_w, const float* __restrict__ fc_b,
                       float* __restrict__ out)
{
    // x frags, ALL 4 k-planes (kg 1..3 stay zero) -> unconditional ds_read_b128
    __shared__ f16x8 xs[2][CH][4][NS];                        // 16 KB
    __shared__ __align__(16) _Float16 h1[2][NS][72];          // 4.6 KB (144B rows)
    __shared__ __align__(16) _Float16 h2[2][NS][72];          // 4.6 KB

    const int tid  = threadIdx.x;
    const int wv   = tid >> 6;       // 0..7
    const int q    = wv & 3;         // unit group within the engine
    const int lane = tid & 63;
    const int col  = lane & 15;      // weight row within tile / sample
    const int kg   = lane >> 4;      // k-group
    const int s0   = blockIdx.x * NS;
    const int ub   = 16 * q + 4 * kg;

    // ---------------- init: zero h + ALL x planes ----------------
    for (int i = tid; i < 2 * NS * 72; i += NTH) {
        ((short*)h1)[i] = 0; ((short*)h2)[i] = 0;
    }
    {
        const f16x8 z8i = {0, 0, 0, 0, 0, 0, 0, 0};
        f16x8* xf = &xs[0][0][0][0];
        for (int i = tid; i < 2 * CH * 4 * NS; i += NTH) xf[i] = z8i;
    }
    __syncthreads();
    if (tid < CH * NS) {             // stage chunk 0 into kg=0 plane
        const int tloc = tid >> 4, ss = tid & 15;
        const float* px = x + ((size_t)(s0 + ss) * TT + tloc) * DD;
        f32x4 a, b;
        a[0] = px[0]; a[1] = px[1]; a[2] = px[2]; a[3] = px[3];
        b[0] = px[4]; b[1] = px[5]; b[2] = px[6]; b[3] = 1.0f;   // bias slot
        xs[0][tloc][0][ss] = pack8(a, b);
    }
    __syncthreads();

    const f32x4 zz = {0, 0, 0, 0};

    if (wv < 4) {
        // ==================== LAYER-0 ENGINE (waves 0-3) ====================
        // Pre-scaled single-fp16 weights: gate rows i,f,o x(-log2e), g x(-2log2e)
        f16x8 W0[4][2], WX[4];
#pragma unroll
        for (int t4 = 0; t4 < 4; ++t4) {
            const float sc = (t4 == 2) ? -2.88539008f : -1.44269504f;
            const int row = 64 * t4 + 16 * q + col;
#pragma unroll
            for (int kf = 0; kf < 2; ++kf) {
                const float* p = w_hh0 + (size_t)row * HH + 32 * kf + 8 * kg;
                W0[t4][kf] = pack8(*(const f32x4*)p * sc, *(const f32x4*)(p + 4) * sc);
            }
            f32x4 a = {0, 0, 0, 0}, b = {0, 0, 0, 0};
            if (kg == 0) {
                const float* p = w_ih0 + (size_t)row * DD;
                a[0] = p[0]; a[1] = p[1]; a[2] = p[2]; a[3] = p[3];
                b[0] = p[4]; b[1] = p[5]; b[2] = p[6];
                b[3] = b_ih0[row] + b_hh0[row];     // bias0 rides k-slot 7
            }
            WX[t4] = pack8(a * sc, b * sc);
        }
        f32x4 c1 = {0, 0, 0, 0};     // holds cs1 = -2log2e * c1

        // loop-invariant pointers (parities compile-time per sub-step)
        const f16x8* xk = &xs[0][0][kg][col];   // step k frag at xk[(k&15)*64]
        const _Float16* r0a = &h1[0][col][8 * kg];
        const _Float16* r0b = &h1[0][col][32 + 8 * kg];
        const _Float16* r1a = &h1[1][col][8 * kg];
        const _Float16* r1b = &h1[1][col][32 + 8 * kg];
        _Float16* wp0 = &h1[0][col][ub];
        _Float16* wp1 = &h1[1][col][ub];

        auto l0_step = [&](int xofs, const _Float16* ra, const _Float16* rb,
                           _Float16* wr) {
            f32x4 a0, a1, a2, a3;
            const f16x8 ax = xk[xofs];
            a0 = MFMA16F(WX[0], ax, zz);
            a1 = MFMA16F(WX[1], ax, zz);
            a2 = MFMA16F(WX[2], ax, zz);
            a3 = MFMA16F(WX[3], ax, zz);
            f16x8 dh = *(const f16x8*)ra;
            a0 = MFMA16F(W0[0][0], dh, a0);
            a1 = MFMA16F(W0[1][0], dh, a1);
            a2 = MFMA16F(W0[2][0], dh, a2);
            a3 = MFMA16F(W0[3][0], dh, a3);
            dh = *(const f16x8*)rb;
            a0 = MFMA16F(W0[0][1], dh, a0);
            a1 = MFMA16F(W0[1][1], dh, a1);
            a2 = MFMA16F(W0[2][1], dh, a2);
            a3 = MFMA16F(W0[3][1], dh, a3);
            cell_update(a0, a1, a2, a3, c1, wr);
        };
        auto refill = [&](int kref) {          // loads chunk starting at kref+CH
            if (tid < CH * NS) {
                const int tloc = tid >> 4, ss = tid & 15;
                const int tg = kref + CH + tloc;
                const float* px = x + ((size_t)(s0 + ss) * TT + tg) * DD;
                f32x4 a, b;
                a[0] = px[0]; a[1] = px[1]; a[2] = px[2]; a[3] = px[3];
                b[0] = px[4]; b[1] = px[5]; b[2] = px[6]; b[3] = 1.0f;
                const int nb = ((kref >> 3) & 1) ^ 1;
                xs[nb][tloc][0][ss] = pack8(a, b);
            }
        };

        // ---- peel k=0 (reads h1[1]=0, writes h1[0]) and k=1 ----
        refill(0);
        l0_step(0, r1a, r1b, wp0);
        __syncthreads();
        l0_step(64, r0a, r0b, wp1);
        __syncthreads();

#pragma unroll 1
        for (int j = 1; j < 84; ++j) {
            const int xofs = ((2 * j) & 15) * 64;
            if ((j & 3) == 0 && j < 80) refill(2 * j);
            l0_step(xofs, r1a, r1b, wp0);        // k=2j   : read h1[1], write h1[0]
            __syncthreads();
            l0_step(xofs + 64, r0a, r0b, wp1);   // k=2j+1 : read h1[0], write h1[1]
            __syncthreads();
        }
        __syncthreads();   // epilogue region k=168 (L0 idle)
    } else {
        // ==================== LAYER-1 ENGINE (waves 4-7) ====================
        f16x8 W1[4][4];   // kf 0..1: w_ih1 (h1 input); kf 2..3: w_hh1 (h2 input)
        f32x4 bias1[4];
#pragma unroll
        for (int t4 = 0; t4 < 4; ++t4) {
            const float sc = (t4 == 2) ? -2.88539008f : -1.44269504f;
            const int row = 64 * t4 + 16 * q + col;
            const int rr  = 64 * t4 + 16 * q + 4 * kg;
            bias1[t4] = (*(const f32x4*)(b_ih1 + rr) + *(const f32x4*)(b_hh1 + rr)) * sc;
#pragma unroll
            for (int kf = 0; kf < 4; ++kf) {
                const float* base = (kf < 2) ? (w_ih1 + (size_t)row * HH + 32 * kf)
                                             : (w_hh1 + (size_t)row * HH + 32 * (kf - 2));
                const float* p = base + 8 * kg;
                W1[t4][kf] = pack8(*(const f32x4*)p * sc, *(const f32x4*)(p + 4) * sc);
            }
        }
        f32x4 c2 = {0, 0, 0, 0};     // holds cs2

        const _Float16* p1a0 = &h1[0][col][8 * kg];
        const _Float16* p1b0 = &h1[0][col][32 + 8 * kg];
        const _Float16* p1a1 = &h1[1][col][8 * kg];
        const _Float16* p1b1 = &h1[1][col][32 + 8 * kg];
        const _Float16* p2a0 = &h2[0][col][8 * kg];
        const _Float16* p2b0 = &h2[0][col][32 + 8 * kg];
        const _Float16* p2a1 = &h2[1][col][8 * kg];
        const _Float16* p2b1 = &h2[1][col][32 + 8 * kg];
        _Float16* q0 = &h2[0][col][ub];
        _Float16* q1 = &h2[1][col][ub];

        auto l1_step = [&](const _Float16* ha, const _Float16* hb,
                           const _Float16* ea, const _Float16* eb, _Float16* wr) {
            f32x4 a0, a1, a2, a3;
            f16x8 dh = *(const f16x8*)ha;
            a0 = MFMA16F(W1[0][0], dh, bias1[0]);
            a1 = MFMA16F(W1[1][0], dh, bias1[1]);
            a2 = MFMA16F(W1[2][0], dh, bias1[2]);
            a3 = MFMA16F(W1[3][0], dh, bias1[3]);
            dh = *(const f16x8*)hb;
            a0 = MFMA16F(W1[0][1], dh, a0);
            a1 = MFMA16F(W1[1][1], dh, a1);
            a2 = MFMA16F(W1[2][1], dh, a2);
            a3 = MFMA16F(W1[3][1], dh, a3);
            dh = *(const f16x8*)ea;
            a0 = MFMA16F(W1[0][2], dh, a0);
            a1 = MFMA16F(W1[1][2], dh, a1);
            a2 = MFMA16F(W1[2][2], dh, a2);
            a3 = MFMA16F(W1[3][2], dh, a3);
            dh = *(const f16x8*)eb;
            a0 = MFMA16F(W1[0][3], dh, a0);
            a1 = MFMA16F(W1[1][3], dh, a1);
            a2 = MFMA16F(W1[2][3], dh, a2);
            a3 = MFMA16F(W1[3][3], dh, a3);
            cell_update(a0, a1, a2, a3, c2, wr);
        };

        // ---- peel k=0 (idle) and k=1 (reads h1[0], h2[1]=0, writes h2[0]) ----
        __syncthreads();
        l1_step(p1a0, p1b0, p2a1, p2b1, q0);
        __syncthreads();

#pragma unroll 1
        for (int j = 1; j < 84; ++j) {
            l1_step(p1a1, p1b1, p2a0, p2b0, q1);   // k=2j   : cell(k-1) -> h2[1]
            __syncthreads();
            l1_step(p1a0, p1b0, p2a1, p2b1, q0);   // k=2j+1 : cell(k-1) -> h2[0]
            __syncthreads();
        }
        // ---- epilogue k=168: cell(167) -> h2[1] ----
        l1_step(p1a1, p1b1, p2a0, p2b0, q1);
        __syncthreads();
    }

    // ---------------- FC head on final h2 = h2(TT-1), slot 1 ----------------
    if (tid < NS * 4) {
        const int s = tid >> 2, k = tid & 3;
        float a = fc_b[k];
#pragma unroll
        for (int j = 0; j < HH; ++j)
            a = fmaf((float)h2[1][s][j], fc_w[k * HH + j], a);
        out[(size_t)(s0 + s) * 4 + k] = a;
    }
}

extern "C" void kernel_launch(void* const* d_in, const int* in_sizes, int n_in,
                              void* d_out, int out_size, void* d_ws, size_t ws_size,
                              hipStream_t stream) {
    const float* x     = (const float*)d_in[0];
    const float* w_ih0 = (const float*)d_in[1];
    const float* w_hh0 = (const float*)d_in[2];
    const float* b_ih0 = (const float*)d_in[3];
    const float* b_hh0 = (const float*)d_in[4];
    const float* w_ih1 = (const float*)d_in[5];
    const float* w_hh1 = (const float*)d_in[6];
    const float* b_ih1 = (const float*)d_in[7];
    const float* b_hh1 = (const float*)d_in[8];
    const float* fc_w  = (const float*)d_in[9];
    const float* fc_b  = (const float*)d_in[10];
    float* out = (float*)d_out;

    dim3 grid(BB / NS), block(NTH);
    weather_lstm_mfma<<<grid, block, 0, stream>>>(
        x, w_ih0, w_hh0, b_ih0, b_hh0,
        w_ih1, w_hh1, b_ih1, b_hh1, fc_w, fc_b, out);
}